// Round 1
// baseline (1956.653 us; speedup 1.0000x reference)
//
#include <hip/hip_runtime.h>

#define EMB_DIM 32
#define NUM_LAYERS 3

// One edge is handled by 8 consecutive threads; thread q of an edge owns
// float4 quad q (4 dims). Gather X[col[e]] (contiguous 128B per edge,
// coalesced across the 8 lanes) and atomic-scatter into out[row[e]].
__global__ void lightgcn_scatter(const float* __restrict__ X,
                                 const float* __restrict__ w,
                                 const int* __restrict__ row,
                                 const int* __restrict__ col,
                                 float* __restrict__ out,
                                 int n_edges) {
    long tid = (long)blockIdx.x * blockDim.x + threadIdx.x;
    int e = (int)(tid >> 3);   // edge index
    int q = (int)(tid & 7);    // quad within the 32-dim row
    if (e >= n_edges) return;

    const int r = row[e];
    const int c = col[e];
    const float wt = w[e];

    const float4 v = *reinterpret_cast<const float4*>(X + (size_t)c * EMB_DIM + q * 4);
    float* o = out + (size_t)r * EMB_DIM + q * 4;

    atomicAdd(o + 0, wt * v.x);
    atomicAdd(o + 1, wt * v.y);
    atomicAdd(o + 2, wt * v.z);
    atomicAdd(o + 3, wt * v.w);
}

extern "C" void kernel_launch(void* const* d_in, const int* in_sizes, int n_in,
                              void* d_out, int out_size, void* d_ws, size_t ws_size,
                              hipStream_t stream) {
    const float* emb = (const float*)d_in[0];
    const float* w   = (const float*)d_in[1];
    const int*   row = (const int*)d_in[2];
    const int*   col = (const int*)d_in[3];
    // d_in[4] = num_layers (device scalar); fixed at 3 for this problem.

    const int n_nodes = in_sizes[0] / EMB_DIM;
    const int n_edges = in_sizes[1];

    float* out = (float*)d_out;
    float* tmp = (float*)d_ws;   // needs n_nodes*32*4 = 12.8 MB of ws

    const size_t xbytes = (size_t)n_nodes * EMB_DIM * sizeof(float);

    const int threads = 256;
    const long total = (long)n_edges * 8;
    const int blocks = (int)((total + threads - 1) / threads);

    // Layer 1: emb -> out
    hipMemsetAsync(d_out, 0, xbytes, stream);
    lightgcn_scatter<<<blocks, threads, 0, stream>>>(emb, w, row, col, out, n_edges);

    // Layer 2: out -> tmp
    hipMemsetAsync(d_ws, 0, xbytes, stream);
    lightgcn_scatter<<<blocks, threads, 0, stream>>>(out, w, row, col, tmp, n_edges);

    // Layer 3: tmp -> out
    hipMemsetAsync(d_out, 0, xbytes, stream);
    lightgcn_scatter<<<blocks, threads, 0, stream>>>(tmp, w, row, col, out, n_edges);
}

// Round 2
// 524.812 us; speedup vs baseline: 3.7283x; 3.7283x over previous
//
#include <hip/hip_runtime.h>

#define EMB_DIM 32

// ---------------- CSR build ----------------

__global__ void hist_rows(const int* __restrict__ row, int* __restrict__ cnt, int n_edges) {
    int e = blockIdx.x * blockDim.x + threadIdx.x;
    if (e >= n_edges) return;
    atomicAdd(&cnt[row[e]], 1);
}

// Single-workgroup scan: 1024 threads, each owns a contiguous chunk.
// Writes exclusive-prefix offsets into off[0..n] and a copy into cursor[0..n-1].
__global__ void scan_offsets(const int* __restrict__ cnt, int* __restrict__ off,
                             int* __restrict__ cursor, int n) {
    __shared__ int lsum[1024];
    const int t = threadIdx.x;
    const int chunk = (n + 1023) / 1024;
    const int lo = t * chunk;
    const int hi = min(lo + chunk, n);

    int s = 0;
    for (int i = lo; i < hi; ++i) s += cnt[i];
    lsum[t] = s;
    __syncthreads();

    // Hillis-Steele inclusive scan over the 1024 block sums
    for (int d = 1; d < 1024; d <<= 1) {
        int add = (t >= d) ? lsum[t - d] : 0;
        __syncthreads();
        lsum[t] += add;
        __syncthreads();
    }

    int run = (t > 0) ? lsum[t - 1] : 0;   // exclusive offset of this chunk
    for (int i = lo; i < hi; ++i) {
        off[i] = run;
        cursor[i] = run;
        run += cnt[i];
    }
    if (t == 0) off[n] = lsum[1023];
    __syncthreads();
}

// Scatter (col, w) pairs into CSR order using per-row cursors.
__global__ void build_colw(const int* __restrict__ row, const int* __restrict__ col,
                           const float* __restrict__ w, int* __restrict__ cursor,
                           int2* __restrict__ colw, int n_edges) {
    int e = blockIdx.x * blockDim.x + threadIdx.x;
    if (e >= n_edges) return;
    int r = row[e];
    int pos = atomicAdd(&cursor[r], 1);
    colw[pos] = make_int2(col[e], __float_as_int(w[e]));
}

// ---------------- atomic-free SpMV layer ----------------
// 8 threads per row; thread q owns float4 quad q of the 32-dim row.
__global__ void spmv_layer(const float* __restrict__ X, const int* __restrict__ off,
                           const int2* __restrict__ colw, float* __restrict__ out,
                           int n_nodes) {
    long tid = (long)blockIdx.x * blockDim.x + threadIdx.x;
    int r = (int)(tid >> 3);
    int q = (int)(tid & 7);
    if (r >= n_nodes) return;

    const int start = off[r];
    const int end   = off[r + 1];

    float4 acc = make_float4(0.f, 0.f, 0.f, 0.f);
    for (int k = start; k < end; ++k) {
        int2 cw = colw[k];                       // 8 lanes broadcast same 8B
        const float wt = __int_as_float(cw.y);
        const float4 v = *reinterpret_cast<const float4*>(X + (size_t)cw.x * EMB_DIM + q * 4);
        acc.x += wt * v.x;
        acc.y += wt * v.y;
        acc.z += wt * v.z;
        acc.w += wt * v.w;
    }
    *reinterpret_cast<float4*>(out + (size_t)r * EMB_DIM + q * 4) = acc;
}

// ---------------- round-1 fallback (atomic scatter) ----------------
__global__ void lightgcn_scatter(const float* __restrict__ X, const float* __restrict__ w,
                                 const int* __restrict__ row, const int* __restrict__ col,
                                 float* __restrict__ out, int n_edges) {
    long tid = (long)blockIdx.x * blockDim.x + threadIdx.x;
    int e = (int)(tid >> 3);
    int q = (int)(tid & 7);
    if (e >= n_edges) return;
    const int r = row[e];
    const int c = col[e];
    const float wt = w[e];
    const float4 v = *reinterpret_cast<const float4*>(X + (size_t)c * EMB_DIM + q * 4);
    float* o = out + (size_t)r * EMB_DIM + q * 4;
    atomicAdd(o + 0, wt * v.x);
    atomicAdd(o + 1, wt * v.y);
    atomicAdd(o + 2, wt * v.z);
    atomicAdd(o + 3, wt * v.w);
}

extern "C" void kernel_launch(void* const* d_in, const int* in_sizes, int n_in,
                              void* d_out, int out_size, void* d_ws, size_t ws_size,
                              hipStream_t stream) {
    const float* emb = (const float*)d_in[0];
    const float* w   = (const float*)d_in[1];
    const int*   row = (const int*)d_in[2];
    const int*   col = (const int*)d_in[3];
    // d_in[4] = num_layers (device scalar); fixed at 3 for this problem.

    const int n_nodes = in_sizes[0] / EMB_DIM;
    const int n_edges = in_sizes[1];

    float* out = (float*)d_out;
    const size_t xbytes = (size_t)n_nodes * EMB_DIM * sizeof(float);

    // ---- workspace layout ----
    const size_t tmpx_off   = 0;
    const size_t cnt_off    = xbytes;                             // n_nodes+2 ints
    const size_t intarr     = ((size_t)(n_nodes + 2) * 4 + 15) & ~(size_t)15;
    const size_t off_off    = cnt_off + intarr;
    const size_t cursor_off = off_off + intarr;
    const size_t colw_off   = (cursor_off + intarr + 15) & ~(size_t)15;
    const size_t need       = colw_off + (size_t)n_edges * 8;

    if (ws_size < need) {
        // Fallback: round-1 atomic path (needs only xbytes of ws)
        float* tmp = (float*)d_ws;
        const int threads = 256;
        const int blocks = (int)(((long)n_edges * 8 + threads - 1) / threads);
        hipMemsetAsync(d_out, 0, xbytes, stream);
        lightgcn_scatter<<<blocks, threads, 0, stream>>>(emb, w, row, col, out, n_edges);
        hipMemsetAsync(d_ws, 0, xbytes, stream);
        lightgcn_scatter<<<blocks, threads, 0, stream>>>(out, w, row, col, tmp, n_edges);
        hipMemsetAsync(d_out, 0, xbytes, stream);
        lightgcn_scatter<<<blocks, threads, 0, stream>>>(tmp, w, row, col, out, n_edges);
        return;
    }

    char* ws = (char*)d_ws;
    float* tmpX   = (float*)(ws + tmpx_off);
    int*   cnt    = (int*)(ws + cnt_off);
    int*   offs   = (int*)(ws + off_off);
    int*   cursor = (int*)(ws + cursor_off);
    int2*  colw   = (int2*)(ws + colw_off);

    const int threads = 256;
    const int eblocks = (n_edges + threads - 1) / threads;

    // ---- build CSR (once; reused for all 3 layers) ----
    hipMemsetAsync(cnt, 0, (size_t)(n_nodes + 1) * 4, stream);
    hist_rows<<<eblocks, threads, 0, stream>>>(row, cnt, n_edges);
    scan_offsets<<<1, 1024, 0, stream>>>(cnt, offs, cursor, n_nodes);
    build_colw<<<eblocks, threads, 0, stream>>>(row, col, w, cursor, colw, n_edges);

    // ---- 3 atomic-free layers ----
    const int rblocks = (int)(((long)n_nodes * 8 + threads - 1) / threads);
    spmv_layer<<<rblocks, threads, 0, stream>>>(emb,  offs, colw, out,  n_nodes);
    spmv_layer<<<rblocks, threads, 0, stream>>>(out,  offs, colw, tmpX, n_nodes);
    spmv_layer<<<rblocks, threads, 0, stream>>>(tmpX, offs, colw, out,  n_nodes);
}

// Round 3
// 292.000 us; speedup vs baseline: 6.7009x; 1.7973x over previous
//
#include <hip/hip_runtime.h>

#define EMB_DIM 32
#define SCAN_T 256
#define SCAN_E 8
#define SCAN_BLOCK (SCAN_T * SCAN_E)   // 2048 elements per block

// ---------------- CSR build ----------------

__global__ void hist_rows(const int* __restrict__ row, int* __restrict__ cnt, int n_edges) {
    int e = blockIdx.x * blockDim.x + threadIdx.x;
    if (e >= n_edges) return;
    atomicAdd(&cnt[row[e]], 1);
}

// Phase 1: per-block sums of 2048-element chunks (coalesced strided reads).
__global__ void scan_block_sums(const int* __restrict__ cnt, int* __restrict__ bsum, int n) {
    const int base = blockIdx.x * SCAN_BLOCK;
    const int t = threadIdx.x;
    int s = 0;
#pragma unroll
    for (int i = 0; i < SCAN_E; ++i) {
        int idx = base + i * SCAN_T + t;
        if (idx < n) s += cnt[idx];
    }
    __shared__ int red[SCAN_T];
    red[t] = s;
    __syncthreads();
    for (int d = SCAN_T / 2; d > 0; d >>= 1) {
        if (t < d) red[t] += red[t + d];
        __syncthreads();
    }
    if (t == 0) bsum[blockIdx.x] = red[0];
}

// Phase 2: exclusive scan of the block sums (single small block, chunked for generality).
__global__ void scan_bsum(int* __restrict__ bsum, int nb, int* __restrict__ off, int n) {
    __shared__ int sh[SCAN_T];
    const int t = threadIdx.x;
    int carry = 0;
    for (int base = 0; base < nb; base += SCAN_T) {
        int v = (base + t < nb) ? bsum[base + t] : 0;
        sh[t] = v;
        __syncthreads();
        for (int d = 1; d < SCAN_T; d <<= 1) {
            int add = (t >= d) ? sh[t - d] : 0;
            __syncthreads();
            sh[t] += add;
            __syncthreads();
        }
        if (base + t < nb) bsum[base + t] = carry + sh[t] - v;   // exclusive
        int chunk_total = sh[SCAN_T - 1];
        __syncthreads();
        carry += chunk_total;
    }
    if (t == 0) off[n] = carry;
}

// Phase 3: in-block scan (thread owns 8 contiguous elems), add block base, write off+cursor.
__global__ void scan_block_write(const int* __restrict__ cnt, const int* __restrict__ bbase,
                                 int* __restrict__ off, int* __restrict__ cursor, int n) {
    const int base = blockIdx.x * SCAN_BLOCK;
    const int t = threadIdx.x;
    const int lo = base + t * SCAN_E;
    int vals[SCAN_E];
#pragma unroll
    for (int i = 0; i < SCAN_E; ++i) {
        int idx = lo + i;
        vals[i] = (idx < n) ? cnt[idx] : 0;
    }
    int tsum = 0;
#pragma unroll
    for (int i = 0; i < SCAN_E; ++i) tsum += vals[i];

    __shared__ int sh[SCAN_T];
    sh[t] = tsum;
    __syncthreads();
    for (int d = 1; d < SCAN_T; d <<= 1) {
        int add = (t >= d) ? sh[t - d] : 0;
        __syncthreads();
        sh[t] += add;
        __syncthreads();
    }
    int run = bbase[blockIdx.x] + sh[t] - tsum;   // exclusive base for this thread
#pragma unroll
    for (int i = 0; i < SCAN_E; ++i) {
        int idx = lo + i;
        if (idx < n) { off[idx] = run; cursor[idx] = run; }
        run += vals[i];
    }
}

// Scatter (col, w) pairs into CSR order using per-row cursors.
__global__ void build_colw(const int* __restrict__ row, const int* __restrict__ col,
                           const float* __restrict__ w, int* __restrict__ cursor,
                           int2* __restrict__ colw, int n_edges) {
    int e = blockIdx.x * blockDim.x + threadIdx.x;
    if (e >= n_edges) return;
    int r = row[e];
    int pos = atomicAdd(&cursor[r], 1);
    colw[pos] = make_int2(col[e], __float_as_int(w[e]));
}

// ---------------- atomic-free SpMV layer ----------------
// 8 threads per row; thread q owns float4 quad q. Unrolled x4 for gather MLP.
__global__ void spmv_layer(const float* __restrict__ X, const int* __restrict__ off,
                           const int2* __restrict__ colw, float* __restrict__ out,
                           int n_nodes) {
    long tid = (long)blockIdx.x * blockDim.x + threadIdx.x;
    int r = (int)(tid >> 3);
    int q = (int)(tid & 7);
    if (r >= n_nodes) return;

    const int start = off[r];
    const int end   = off[r + 1];

    float4 acc = make_float4(0.f, 0.f, 0.f, 0.f);
    int k = start;
    for (; k + 4 <= end; k += 4) {
        int2 cw0 = colw[k + 0];
        int2 cw1 = colw[k + 1];
        int2 cw2 = colw[k + 2];
        int2 cw3 = colw[k + 3];
        const float4 v0 = *reinterpret_cast<const float4*>(X + (size_t)cw0.x * EMB_DIM + q * 4);
        const float4 v1 = *reinterpret_cast<const float4*>(X + (size_t)cw1.x * EMB_DIM + q * 4);
        const float4 v2 = *reinterpret_cast<const float4*>(X + (size_t)cw2.x * EMB_DIM + q * 4);
        const float4 v3 = *reinterpret_cast<const float4*>(X + (size_t)cw3.x * EMB_DIM + q * 4);
        const float w0 = __int_as_float(cw0.y), w1 = __int_as_float(cw1.y);
        const float w2 = __int_as_float(cw2.y), w3 = __int_as_float(cw3.y);
        acc.x += w0 * v0.x; acc.y += w0 * v0.y; acc.z += w0 * v0.z; acc.w += w0 * v0.w;
        acc.x += w1 * v1.x; acc.y += w1 * v1.y; acc.z += w1 * v1.z; acc.w += w1 * v1.w;
        acc.x += w2 * v2.x; acc.y += w2 * v2.y; acc.z += w2 * v2.z; acc.w += w2 * v2.w;
        acc.x += w3 * v3.x; acc.y += w3 * v3.y; acc.z += w3 * v3.z; acc.w += w3 * v3.w;
    }
    for (; k < end; ++k) {
        int2 cw = colw[k];
        const float wt = __int_as_float(cw.y);
        const float4 v = *reinterpret_cast<const float4*>(X + (size_t)cw.x * EMB_DIM + q * 4);
        acc.x += wt * v.x; acc.y += wt * v.y; acc.z += wt * v.z; acc.w += wt * v.w;
    }
    *reinterpret_cast<float4*>(out + (size_t)r * EMB_DIM + q * 4) = acc;
}

// ---------------- round-1 fallback (atomic scatter) ----------------
__global__ void lightgcn_scatter(const float* __restrict__ X, const float* __restrict__ w,
                                 const int* __restrict__ row, const int* __restrict__ col,
                                 float* __restrict__ out, int n_edges) {
    long tid = (long)blockIdx.x * blockDim.x + threadIdx.x;
    int e = (int)(tid >> 3);
    int q = (int)(tid & 7);
    if (e >= n_edges) return;
    const int r = row[e];
    const int c = col[e];
    const float wt = w[e];
    const float4 v = *reinterpret_cast<const float4*>(X + (size_t)c * EMB_DIM + q * 4);
    float* o = out + (size_t)r * EMB_DIM + q * 4;
    atomicAdd(o + 0, wt * v.x);
    atomicAdd(o + 1, wt * v.y);
    atomicAdd(o + 2, wt * v.z);
    atomicAdd(o + 3, wt * v.w);
}

extern "C" void kernel_launch(void* const* d_in, const int* in_sizes, int n_in,
                              void* d_out, int out_size, void* d_ws, size_t ws_size,
                              hipStream_t stream) {
    const float* emb = (const float*)d_in[0];
    const float* w   = (const float*)d_in[1];
    const int*   row = (const int*)d_in[2];
    const int*   col = (const int*)d_in[3];
    // d_in[4] = num_layers (device scalar); fixed at 3 for this problem.

    const int n_nodes = in_sizes[0] / EMB_DIM;
    const int n_edges = in_sizes[1];

    float* out = (float*)d_out;
    const size_t xbytes = (size_t)n_nodes * EMB_DIM * sizeof(float);

    const int nscan = (n_nodes + SCAN_BLOCK - 1) / SCAN_BLOCK;

    // ---- workspace layout ----
    const size_t tmpx_off   = 0;
    const size_t cnt_off    = xbytes;
    const size_t intarr     = ((size_t)(n_nodes + 2) * 4 + 15) & ~(size_t)15;
    const size_t off_off    = cnt_off + intarr;
    const size_t cursor_off = off_off + intarr;
    const size_t bsum_off   = cursor_off + intarr;
    const size_t bsum_sz    = ((size_t)(nscan + 1) * 4 + 15) & ~(size_t)15;
    const size_t colw_off   = (bsum_off + bsum_sz + 15) & ~(size_t)15;
    const size_t need       = colw_off + (size_t)n_edges * 8;

    if (ws_size < need) {
        // Fallback: atomic path (needs only xbytes of ws)
        float* tmp = (float*)d_ws;
        const int threads = 256;
        const int blocks = (int)(((long)n_edges * 8 + threads - 1) / threads);
        hipMemsetAsync(d_out, 0, xbytes, stream);
        lightgcn_scatter<<<blocks, threads, 0, stream>>>(emb, w, row, col, out, n_edges);
        hipMemsetAsync(d_ws, 0, xbytes, stream);
        lightgcn_scatter<<<blocks, threads, 0, stream>>>(out, w, row, col, tmp, n_edges);
        hipMemsetAsync(d_out, 0, xbytes, stream);
        lightgcn_scatter<<<blocks, threads, 0, stream>>>(tmp, w, row, col, out, n_edges);
        return;
    }

    char* ws = (char*)d_ws;
    float* tmpX   = (float*)(ws + tmpx_off);
    int*   cnt    = (int*)(ws + cnt_off);
    int*   offs   = (int*)(ws + off_off);
    int*   cursor = (int*)(ws + cursor_off);
    int*   bsum   = (int*)(ws + bsum_off);
    int2*  colw   = (int2*)(ws + colw_off);

    const int threads = 256;
    const int eblocks = (n_edges + threads - 1) / threads;

    // ---- build CSR (once; reused for all 3 layers) ----
    hipMemsetAsync(cnt, 0, (size_t)(n_nodes + 1) * 4, stream);
    hist_rows<<<eblocks, threads, 0, stream>>>(row, cnt, n_edges);
    scan_block_sums<<<nscan, SCAN_T, 0, stream>>>(cnt, bsum, n_nodes);
    scan_bsum<<<1, SCAN_T, 0, stream>>>(bsum, nscan, offs, n_nodes);
    scan_block_write<<<nscan, SCAN_T, 0, stream>>>(cnt, bsum, offs, cursor, n_nodes);
    build_colw<<<eblocks, threads, 0, stream>>>(row, col, w, cursor, colw, n_edges);

    // ---- 3 atomic-free layers ----
    const int rblocks = (int)(((long)n_nodes * 8 + threads - 1) / threads);
    spmv_layer<<<rblocks, threads, 0, stream>>>(emb,  offs, colw, out,  n_nodes);
    spmv_layer<<<rblocks, threads, 0, stream>>>(out,  offs, colw, tmpX, n_nodes);
    spmv_layer<<<rblocks, threads, 0, stream>>>(tmpX, offs, colw, out,  n_nodes);
}

// Round 4
// 278.897 us; speedup vs baseline: 7.0157x; 1.0470x over previous
//
#include <hip/hip_runtime.h>

#define EMB_DIM 32
#define BSHIFT 7
#define BROWS 128            // rows per bucket (1<<BSHIFT)
#define NCHUNK 8             // write-locality chunks (~XCDs)
#define COLBITS 17           // col < 131072

// ---------------- bucketed CSR build ----------------

// k1: per-(bucket,chunk) histogram. chunk = blockIdx%8 — must match pass1_scatter's mapping.
__global__ void bucket_hist(const int* __restrict__ row, int* __restrict__ bcnt, int n_edges) {
    int e = blockIdx.x * blockDim.x + threadIdx.x;
    if (e >= n_edges) return;
    int c = blockIdx.x & (NCHUNK - 1);
    atomicAdd(&bcnt[(row[e] >> BSHIFT) * NCHUNK + c], 1);
}

// k2: single-block exclusive scan of m=(nb*NCHUNK) counts -> bstart, bcursor; also off[n]=total.
__global__ void scan_global(const int* __restrict__ bcnt, int m,
                            int* __restrict__ bstart, int* __restrict__ bcursor,
                            int* __restrict__ off, int n_nodes) {
    __shared__ int sh[1024];
    const int t = threadIdx.x;
    const int chunk = (m + 1023) / 1024;
    const int lo = t * chunk;
    const int hi = min(lo + chunk, m);

    int s = 0;
    for (int i = lo; i < hi; ++i) s += bcnt[i];
    sh[t] = s;
    __syncthreads();
    for (int d = 1; d < 1024; d <<= 1) {
        int add = (t >= d) ? sh[t - d] : 0;
        __syncthreads();
        sh[t] += add;
        __syncthreads();
    }
    int run = (t > 0) ? sh[t - 1] : 0;
    for (int i = lo; i < hi; ++i) {
        bstart[i] = run;
        bcursor[i] = run;
        run += bcnt[i];
    }
    if (t == 0) {
        bstart[m] = sh[1023];          // total = n_edges
        off[n_nodes] = sh[1023];
    }
}

// k3: scatter edges into bucket-grouped ebuf. Same grid geometry & chunk formula as k1.
__global__ void pass1_scatter(const int* __restrict__ row, const int* __restrict__ col,
                              const float* __restrict__ w, int* __restrict__ bcursor,
                              int2* __restrict__ ebuf, int n_edges) {
    int e = blockIdx.x * blockDim.x + threadIdx.x;
    if (e >= n_edges) return;
    int c = blockIdx.x & (NCHUNK - 1);
    int r = row[e];
    int pos = atomicAdd(&bcursor[(r >> BSHIFT) * NCHUNK + c], 1);
    ebuf[pos] = make_int2(((r & (BROWS - 1)) << COLBITS) | col[e], __float_as_int(w[e]));
}

// k4: one block per bucket. LDS 128-row hist + scan -> off[r]; permute bucket segment
// into row order (writes stay within the bucket's contiguous L2-resident region).
__global__ void pass2_localize(const int2* __restrict__ ebuf, const int* __restrict__ bstart,
                               int2* __restrict__ colw, int* __restrict__ off, int n_nodes) {
    const int b = blockIdx.x;
    const int base = bstart[b * NCHUNK];
    const int endp = bstart[(b + 1) * NCHUNK];
    const int t = threadIdx.x;

    __shared__ int cnt[BROWS];
    __shared__ int scn[BROWS];
    __shared__ int cur[BROWS];

    if (t < BROWS) cnt[t] = 0;
    __syncthreads();

    for (int i = base + t; i < endp; i += blockDim.x)
        atomicAdd(&cnt[ebuf[i].x >> COLBITS], 1);
    __syncthreads();

    if (t < BROWS) scn[t] = cnt[t];
    __syncthreads();
    for (int d = 1; d < BROWS; d <<= 1) {
        int add = (t < BROWS && t >= d) ? scn[t - d] : 0;
        __syncthreads();
        if (t < BROWS) scn[t] += add;
        __syncthreads();
    }
    if (t < BROWS) {
        int e0 = scn[t] - cnt[t];          // exclusive local offset
        int r = b * BROWS + t;
        if (r < n_nodes) off[r] = base + e0;
        cur[t] = e0;
    }
    __syncthreads();

    for (int i = base + t; i < endp; i += blockDim.x) {
        int2 ev = ebuf[i];
        int lr = ev.x >> COLBITS;
        int pos = base + atomicAdd(&cur[lr], 1);
        colw[pos] = make_int2(ev.x & ((1 << COLBITS) - 1), ev.y);
    }
}

// ---------------- atomic-free SpMV layer ----------------
// 8 threads per row; thread q owns float4 quad q. Unrolled x4 for gather MLP.
__global__ void spmv_layer(const float* __restrict__ X, const int* __restrict__ off,
                           const int2* __restrict__ colw, float* __restrict__ out,
                           int n_nodes) {
    long tid = (long)blockIdx.x * blockDim.x + threadIdx.x;
    int r = (int)(tid >> 3);
    int q = (int)(tid & 7);
    if (r >= n_nodes) return;

    const int start = off[r];
    const int end   = off[r + 1];

    float4 acc = make_float4(0.f, 0.f, 0.f, 0.f);
    int k = start;
    for (; k + 4 <= end; k += 4) {
        int2 cw0 = colw[k + 0];
        int2 cw1 = colw[k + 1];
        int2 cw2 = colw[k + 2];
        int2 cw3 = colw[k + 3];
        const float4 v0 = *reinterpret_cast<const float4*>(X + (size_t)cw0.x * EMB_DIM + q * 4);
        const float4 v1 = *reinterpret_cast<const float4*>(X + (size_t)cw1.x * EMB_DIM + q * 4);
        const float4 v2 = *reinterpret_cast<const float4*>(X + (size_t)cw2.x * EMB_DIM + q * 4);
        const float4 v3 = *reinterpret_cast<const float4*>(X + (size_t)cw3.x * EMB_DIM + q * 4);
        const float w0 = __int_as_float(cw0.y), w1 = __int_as_float(cw1.y);
        const float w2 = __int_as_float(cw2.y), w3 = __int_as_float(cw3.y);
        acc.x += w0 * v0.x; acc.y += w0 * v0.y; acc.z += w0 * v0.z; acc.w += w0 * v0.w;
        acc.x += w1 * v1.x; acc.y += w1 * v1.y; acc.z += w1 * v1.z; acc.w += w1 * v1.w;
        acc.x += w2 * v2.x; acc.y += w2 * v2.y; acc.z += w2 * v2.z; acc.w += w2 * v2.w;
        acc.x += w3 * v3.x; acc.y += w3 * v3.y; acc.z += w3 * v3.z; acc.w += w3 * v3.w;
    }
    for (; k < end; ++k) {
        int2 cw = colw[k];
        const float wt = __int_as_float(cw.y);
        const float4 v = *reinterpret_cast<const float4*>(X + (size_t)cw.x * EMB_DIM + q * 4);
        acc.x += wt * v.x; acc.y += wt * v.y; acc.z += wt * v.z; acc.w += wt * v.w;
    }
    *reinterpret_cast<float4*>(out + (size_t)r * EMB_DIM + q * 4) = acc;
}

// ---------------- fallback (atomic scatter) ----------------
__global__ void lightgcn_scatter(const float* __restrict__ X, const float* __restrict__ w,
                                 const int* __restrict__ row, const int* __restrict__ col,
                                 float* __restrict__ out, int n_edges) {
    long tid = (long)blockIdx.x * blockDim.x + threadIdx.x;
    int e = (int)(tid >> 3);
    int q = (int)(tid & 7);
    if (e >= n_edges) return;
    const int r = row[e];
    const int c = col[e];
    const float wt = w[e];
    const float4 v = *reinterpret_cast<const float4*>(X + (size_t)c * EMB_DIM + q * 4);
    float* o = out + (size_t)r * EMB_DIM + q * 4;
    atomicAdd(o + 0, wt * v.x);
    atomicAdd(o + 1, wt * v.y);
    atomicAdd(o + 2, wt * v.z);
    atomicAdd(o + 3, wt * v.w);
}

extern "C" void kernel_launch(void* const* d_in, const int* in_sizes, int n_in,
                              void* d_out, int out_size, void* d_ws, size_t ws_size,
                              hipStream_t stream) {
    const float* emb = (const float*)d_in[0];
    const float* w   = (const float*)d_in[1];
    const int*   row = (const int*)d_in[2];
    const int*   col = (const int*)d_in[3];
    // d_in[4] = num_layers (device scalar); fixed at 3 for this problem.

    const int n_nodes = in_sizes[0] / EMB_DIM;
    const int n_edges = in_sizes[1];

    float* out = (float*)d_out;
    const size_t xbytes = (size_t)n_nodes * EMB_DIM * sizeof(float);

    const int nb = (n_nodes + BROWS - 1) / BROWS;     // buckets
    const int m  = nb * NCHUNK;                        // (bucket,chunk) counters

    // ---- workspace layout ----
    // ebuf (reused as tmpX after pass2) | colw | off | bcnt | bstart | bcursor
    const size_t ebuf_off   = 0;
    const size_t ebuf_sz    = (((size_t)n_edges * 8 > xbytes ? (size_t)n_edges * 8 : xbytes) + 15) & ~(size_t)15;
    const size_t colw_off   = ebuf_off + ebuf_sz;
    const size_t colw_sz    = ((size_t)n_edges * 8 + 15) & ~(size_t)15;
    const size_t off_off    = colw_off + colw_sz;
    const size_t off_sz     = ((size_t)(n_nodes + 2) * 4 + 15) & ~(size_t)15;
    const size_t bcnt_off   = off_off + off_sz;
    const size_t cntarr_sz  = ((size_t)(m + 2) * 4 + 15) & ~(size_t)15;
    const size_t bstart_off = bcnt_off + cntarr_sz;
    const size_t bcur_off   = bstart_off + cntarr_sz;
    const size_t need       = bcur_off + cntarr_sz;

    if (ws_size < need) {
        // Fallback: atomic path (needs only xbytes of ws)
        float* tmp = (float*)d_ws;
        const int threads = 256;
        const int blocks = (int)(((long)n_edges * 8 + threads - 1) / threads);
        hipMemsetAsync(d_out, 0, xbytes, stream);
        lightgcn_scatter<<<blocks, threads, 0, stream>>>(emb, w, row, col, out, n_edges);
        hipMemsetAsync(d_ws, 0, xbytes, stream);
        lightgcn_scatter<<<blocks, threads, 0, stream>>>(out, w, row, col, tmp, n_edges);
        hipMemsetAsync(d_out, 0, xbytes, stream);
        lightgcn_scatter<<<blocks, threads, 0, stream>>>(tmp, w, row, col, out, n_edges);
        return;
    }

    char* ws = (char*)d_ws;
    int2*  ebuf   = (int2*)(ws + ebuf_off);
    float* tmpX   = (float*)(ws + ebuf_off);   // alias: ebuf dead after pass2
    int2*  colw   = (int2*)(ws + colw_off);
    int*   offs   = (int*)(ws + off_off);
    int*   bcnt   = (int*)(ws + bcnt_off);
    int*   bstart = (int*)(ws + bstart_off);
    int*   bcursor= (int*)(ws + bcur_off);

    const int threads = 256;
    const int eblocks = (n_edges + threads - 1) / threads;

    // ---- build bucketed CSR (once; reused for all 3 layers) ----
    hipMemsetAsync(bcnt, 0, (size_t)m * 4, stream);
    bucket_hist<<<eblocks, threads, 0, stream>>>(row, bcnt, n_edges);
    scan_global<<<1, 1024, 0, stream>>>(bcnt, m, bstart, bcursor, offs, n_nodes);
    pass1_scatter<<<eblocks, threads, 0, stream>>>(row, col, w, bcursor, ebuf, n_edges);
    pass2_localize<<<nb, threads, 0, stream>>>(ebuf, bstart, colw, offs, n_nodes);

    // ---- 3 atomic-free layers ----
    const int rblocks = (int)(((long)n_nodes * 8 + threads - 1) / threads);
    spmv_layer<<<rblocks, threads, 0, stream>>>(emb,  offs, colw, out,  n_nodes);
    spmv_layer<<<rblocks, threads, 0, stream>>>(out,  offs, colw, tmpX, n_nodes);
    spmv_layer<<<rblocks, threads, 0, stream>>>(tmpX, offs, colw, out,  n_nodes);
}

// Round 5
// 205.871 us; speedup vs baseline: 9.5043x; 1.3547x over previous
//
#include <hip/hip_runtime.h>

#define EMB_DIM 32
#define CB_SHIFT 10
#define CB_ROWS 1024          // rows per coarse bucket
#define COLBITS 17            // col < 131072
#define EPB 4096              // edges per partition block
#define P1_T 256

// ---------------- radix-partition CSR build ----------------

// k1: per-(block,bucket) histogram. LDS hist over <=128 coarse buckets.
__global__ void coarse_count(const int* __restrict__ row, int* __restrict__ C,
                             int n_edges, int ncb) {
    __shared__ int h[128];
    const int t = threadIdx.x;
    if (t < 128) h[t] = 0;
    __syncthreads();
    const int base = blockIdx.x * EPB;
    const int end = min(base + EPB, n_edges);
    for (int i = base + t; i < end; i += P1_T)
        atomicAdd(&h[row[i] >> CB_SHIFT], 1);
    __syncthreads();
    if (t < ncb) C[blockIdx.x * ncb + t] = h[t];
}

// k2: single-block exclusive scan of C in bucket-major order (in place).
// After this, C[k*ncb+b] = global start of block k's run within bucket b,
// and C[b] (block 0's entry) = segment start of bucket b. off[n]=total.
__global__ void coarse_scan(int* __restrict__ C, int nblk, int ncb,
                            int* __restrict__ off, int n_nodes) {
    __shared__ int sh[1024];
    const int t = threadIdx.x;
    const int M = nblk * ncb;
    const int chunk = (M + 1023) / 1024;
    const int lo = t * chunk;
    const int hi = min(lo + chunk, M);

    int s = 0;
    for (int i = lo; i < hi; ++i) {
        int b = i / nblk, k = i - b * nblk;
        s += C[k * ncb + b];
    }
    sh[t] = s;
    __syncthreads();
    for (int d = 1; d < 1024; d <<= 1) {
        int add = (t >= d) ? sh[t - d] : 0;
        __syncthreads();
        sh[t] += add;
        __syncthreads();
    }
    int run = (t > 0) ? sh[t - 1] : 0;
    for (int i = lo; i < hi; ++i) {
        int b = i / nblk, k = i - b * nblk;
        int idx = k * ncb + b;
        int c = C[idx];
        C[idx] = run;
        run += c;
    }
    if (t == 0) off[n_nodes] = sh[1023];
}

// k3: scatter edges into bucket-grouped ebuf. Each (block,bucket) run is
// contiguous and written by a single CU -> near-1x write amplification.
__global__ void coarse_scatter(const int* __restrict__ row, const int* __restrict__ col,
                               const float* __restrict__ w, const int* __restrict__ O,
                               int2* __restrict__ ebuf, int n_edges, int ncb) {
    __shared__ int cur[128];
    const int t = threadIdx.x;
    if (t < ncb) cur[t] = O[blockIdx.x * ncb + t];
    __syncthreads();
    const int base = blockIdx.x * EPB;
    const int end = min(base + EPB, n_edges);
    for (int i = base + t; i < end; i += P1_T) {
        int r = row[i];
        int pos = atomicAdd(&cur[r >> CB_SHIFT], 1);
        ebuf[pos] = make_int2(((r & (CB_ROWS - 1)) << COLBITS) | col[i], __float_as_int(w[i]));
    }
}

// k4: one block per coarse bucket. LDS 1024-row hist + scan -> off[r];
// permute the bucket's contiguous (L2-resident) segment into row order.
__global__ void fine_localize(const int2* __restrict__ ebuf, const int* __restrict__ O,
                              int ncb, int n_edges,
                              int2* __restrict__ colw, int* __restrict__ off, int n_nodes) {
    const int b = blockIdx.x;
    const int base = O[b];                               // C[0*ncb + b]
    const int endp = (b + 1 < ncb) ? O[b + 1] : n_edges;
    const int t = threadIdx.x;

    __shared__ int cnt[CB_ROWS];
    __shared__ int scn[CB_ROWS];
    __shared__ int cur[CB_ROWS];

    cnt[t] = 0;
    __syncthreads();
    for (int i = base + t; i < endp; i += CB_ROWS)
        atomicAdd(&cnt[ebuf[i].x >> COLBITS], 1);
    __syncthreads();

    scn[t] = cnt[t];
    __syncthreads();
    for (int d = 1; d < CB_ROWS; d <<= 1) {
        int add = (t >= d) ? scn[t - d] : 0;
        __syncthreads();
        scn[t] += add;
        __syncthreads();
    }
    const int e0 = scn[t] - cnt[t];                       // exclusive local offset
    const int r = b * CB_ROWS + t;
    if (r < n_nodes) off[r] = base + e0;
    cur[t] = e0;
    __syncthreads();

    for (int i = base + t; i < endp; i += CB_ROWS) {
        int2 ev = ebuf[i];
        int lr = ev.x >> COLBITS;
        int pos = base + atomicAdd(&cur[lr], 1);
        colw[pos] = make_int2(ev.x & ((1 << COLBITS) - 1), ev.y);
    }
}

// ---------------- atomic-free SpMV layer ----------------
// 8 threads per row; thread q owns float4 quad q. Unrolled x4 for gather MLP.
__global__ void spmv_layer(const float* __restrict__ X, const int* __restrict__ off,
                           const int2* __restrict__ colw, float* __restrict__ out,
                           int n_nodes) {
    long tid = (long)blockIdx.x * blockDim.x + threadIdx.x;
    int r = (int)(tid >> 3);
    int q = (int)(tid & 7);
    if (r >= n_nodes) return;

    const int start = off[r];
    const int end   = off[r + 1];

    float4 acc = make_float4(0.f, 0.f, 0.f, 0.f);
    int k = start;
    for (; k + 4 <= end; k += 4) {
        int2 cw0 = colw[k + 0];
        int2 cw1 = colw[k + 1];
        int2 cw2 = colw[k + 2];
        int2 cw3 = colw[k + 3];
        const float4 v0 = *reinterpret_cast<const float4*>(X + (size_t)cw0.x * EMB_DIM + q * 4);
        const float4 v1 = *reinterpret_cast<const float4*>(X + (size_t)cw1.x * EMB_DIM + q * 4);
        const float4 v2 = *reinterpret_cast<const float4*>(X + (size_t)cw2.x * EMB_DIM + q * 4);
        const float4 v3 = *reinterpret_cast<const float4*>(X + (size_t)cw3.x * EMB_DIM + q * 4);
        const float w0 = __int_as_float(cw0.y), w1 = __int_as_float(cw1.y);
        const float w2 = __int_as_float(cw2.y), w3 = __int_as_float(cw3.y);
        acc.x += w0 * v0.x; acc.y += w0 * v0.y; acc.z += w0 * v0.z; acc.w += w0 * v0.w;
        acc.x += w1 * v1.x; acc.y += w1 * v1.y; acc.z += w1 * v1.z; acc.w += w1 * v1.w;
        acc.x += w2 * v2.x; acc.y += w2 * v2.y; acc.z += w2 * v2.z; acc.w += w2 * v2.w;
        acc.x += w3 * v3.x; acc.y += w3 * v3.y; acc.z += w3 * v3.z; acc.w += w3 * v3.w;
    }
    for (; k < end; ++k) {
        int2 cw = colw[k];
        const float wt = __int_as_float(cw.y);
        const float4 v = *reinterpret_cast<const float4*>(X + (size_t)cw.x * EMB_DIM + q * 4);
        acc.x += wt * v.x; acc.y += wt * v.y; acc.z += wt * v.z; acc.w += wt * v.w;
    }
    *reinterpret_cast<float4*>(out + (size_t)r * EMB_DIM + q * 4) = acc;
}

// ---------------- fallback (atomic scatter) ----------------
__global__ void lightgcn_scatter(const float* __restrict__ X, const float* __restrict__ w,
                                 const int* __restrict__ row, const int* __restrict__ col,
                                 float* __restrict__ out, int n_edges) {
    long tid = (long)blockIdx.x * blockDim.x + threadIdx.x;
    int e = (int)(tid >> 3);
    int q = (int)(tid & 7);
    if (e >= n_edges) return;
    const int r = row[e];
    const int c = col[e];
    const float wt = w[e];
    const float4 v = *reinterpret_cast<const float4*>(X + (size_t)c * EMB_DIM + q * 4);
    float* o = out + (size_t)r * EMB_DIM + q * 4;
    atomicAdd(o + 0, wt * v.x);
    atomicAdd(o + 1, wt * v.y);
    atomicAdd(o + 2, wt * v.z);
    atomicAdd(o + 3, wt * v.w);
}

extern "C" void kernel_launch(void* const* d_in, const int* in_sizes, int n_in,
                              void* d_out, int out_size, void* d_ws, size_t ws_size,
                              hipStream_t stream) {
    const float* emb = (const float*)d_in[0];
    const float* w   = (const float*)d_in[1];
    const int*   row = (const int*)d_in[2];
    const int*   col = (const int*)d_in[3];
    // d_in[4] = num_layers (device scalar); fixed at 3 for this problem.

    const int n_nodes = in_sizes[0] / EMB_DIM;
    const int n_edges = in_sizes[1];

    float* out = (float*)d_out;
    const size_t xbytes = (size_t)n_nodes * EMB_DIM * sizeof(float);

    const int ncb  = (n_nodes + CB_ROWS - 1) / CB_ROWS;   // coarse buckets (98)
    const int nblk = (n_edges + EPB - 1) / EPB;           // partition blocks (391)

    // ---- workspace layout ----
    // ebuf (reused as tmpX after fine_localize) | colw | off | C
    const size_t ebuf_off = 0;
    const size_t ebuf_sz  = (((size_t)n_edges * 8 > xbytes ? (size_t)n_edges * 8 : xbytes) + 15) & ~(size_t)15;
    const size_t colw_off = ebuf_off + ebuf_sz;
    const size_t colw_sz  = ((size_t)n_edges * 8 + 15) & ~(size_t)15;
    const size_t off_off  = colw_off + colw_sz;
    const size_t off_sz   = ((size_t)(n_nodes + 2) * 4 + 15) & ~(size_t)15;
    const size_t C_off    = off_off + off_sz;
    const size_t C_sz     = ((size_t)nblk * ncb * 4 + 15) & ~(size_t)15;
    const size_t need     = C_off + C_sz;

    if (ws_size < need || ncb > 128) {
        // Fallback: atomic path (needs only xbytes of ws)
        float* tmp = (float*)d_ws;
        const int threads = 256;
        const int blocks = (int)(((long)n_edges * 8 + threads - 1) / threads);
        hipMemsetAsync(d_out, 0, xbytes, stream);
        lightgcn_scatter<<<blocks, threads, 0, stream>>>(emb, w, row, col, out, n_edges);
        hipMemsetAsync(d_ws, 0, xbytes, stream);
        lightgcn_scatter<<<blocks, threads, 0, stream>>>(out, w, row, col, tmp, n_edges);
        hipMemsetAsync(d_out, 0, xbytes, stream);
        lightgcn_scatter<<<blocks, threads, 0, stream>>>(tmp, w, row, col, out, n_edges);
        return;
    }

    char* ws = (char*)d_ws;
    int2*  ebuf = (int2*)(ws + ebuf_off);
    float* tmpX = (float*)(ws + ebuf_off);   // alias: ebuf dead after fine_localize
    int2*  colw = (int2*)(ws + colw_off);
    int*   offs = (int*)(ws + off_off);
    int*   C    = (int*)(ws + C_off);

    // ---- build CSR (once; reused for all 3 layers) ----
    coarse_count<<<nblk, P1_T, 0, stream>>>(row, C, n_edges, ncb);
    coarse_scan<<<1, 1024, 0, stream>>>(C, nblk, ncb, offs, n_nodes);
    coarse_scatter<<<nblk, P1_T, 0, stream>>>(row, col, w, C, ebuf, n_edges, ncb);
    fine_localize<<<ncb, CB_ROWS, 0, stream>>>(ebuf, C, ncb, n_edges, colw, offs, n_nodes);

    // ---- 3 atomic-free layers ----
    const int threads = 256;
    const int rblocks = (int)(((long)n_nodes * 8 + threads - 1) / threads);
    spmv_layer<<<rblocks, threads, 0, stream>>>(emb,  offs, colw, out,  n_nodes);
    spmv_layer<<<rblocks, threads, 0, stream>>>(out,  offs, colw, tmpX, n_nodes);
    spmv_layer<<<rblocks, threads, 0, stream>>>(tmpX, offs, colw, out,  n_nodes);
}

// Round 6
// 154.217 us; speedup vs baseline: 12.6877x; 1.3349x over previous
//
#include <hip/hip_runtime.h>

#define EMB_DIM 32
#define CB_SHIFT 10
#define CB_ROWS 1024          // rows per coarse bucket
#define COLBITS 17            // col < 131072
#define EPB 4096              // edges per partition block
#define P1_T 256
#define SCAN_T 256
#define SCAN_E 8
#define SCAN_BLOCK (SCAN_T * SCAN_E)   // 2048 elements per scan block

// ---------------- radix-partition CSR build ----------------

// k1: per-(block,bucket) histogram, written TRANSPOSED: C[bucket*nblk + block].
// Bucket-major layout makes the subsequent exclusive scan contiguous.
__global__ void coarse_count(const int* __restrict__ row, int* __restrict__ C,
                             int n_edges, int ncb, int nblk) {
    __shared__ int h[128];
    const int t = threadIdx.x;
    if (t < 128) h[t] = 0;
    __syncthreads();
    const int base = blockIdx.x * EPB;
    const int end = min(base + EPB, n_edges);
    for (int i = base + t; i < end; i += P1_T)
        atomicAdd(&h[row[i] >> CB_SHIFT], 1);
    __syncthreads();
    if (t < ncb) C[t * nblk + blockIdx.x] = h[t];
}

// ---- hierarchical exclusive scan over C[0..M), in place ----

__global__ void scan_block_sums(const int* __restrict__ C, int* __restrict__ bsum, int M) {
    const int base = blockIdx.x * SCAN_BLOCK;
    const int t = threadIdx.x;
    int s = 0;
#pragma unroll
    for (int i = 0; i < SCAN_E; ++i) {
        int idx = base + i * SCAN_T + t;
        if (idx < M) s += C[idx];
    }
    __shared__ int red[SCAN_T];
    red[t] = s;
    __syncthreads();
    for (int d = SCAN_T / 2; d > 0; d >>= 1) {
        if (t < d) red[t] += red[t + d];
        __syncthreads();
    }
    if (t == 0) bsum[blockIdx.x] = red[0];
}

__global__ void scan_bsum(int* __restrict__ bsum, int nbs, int* __restrict__ off, int n_nodes) {
    __shared__ int sh[SCAN_T];
    const int t = threadIdx.x;
    int carry = 0;
    for (int base = 0; base < nbs; base += SCAN_T) {
        int v = (base + t < nbs) ? bsum[base + t] : 0;
        sh[t] = v;
        __syncthreads();
        for (int d = 1; d < SCAN_T; d <<= 1) {
            int add = (t >= d) ? sh[t - d] : 0;
            __syncthreads();
            sh[t] += add;
            __syncthreads();
        }
        if (base + t < nbs) bsum[base + t] = carry + sh[t] - v;   // exclusive
        int chunk_total = sh[SCAN_T - 1];
        __syncthreads();
        carry += chunk_total;
    }
    if (t == 0) off[n_nodes] = carry;    // total = n_edges
}

__global__ void scan_block_write(int* __restrict__ C, const int* __restrict__ bbase, int M) {
    const int base = blockIdx.x * SCAN_BLOCK;
    const int t = threadIdx.x;
    const int lo = base + t * SCAN_E;
    int vals[SCAN_E];
#pragma unroll
    for (int i = 0; i < SCAN_E; ++i) {
        int idx = lo + i;
        vals[i] = (idx < M) ? C[idx] : 0;
    }
    int tsum = 0;
#pragma unroll
    for (int i = 0; i < SCAN_E; ++i) tsum += vals[i];

    __shared__ int sh[SCAN_T];
    sh[t] = tsum;
    __syncthreads();
    for (int d = 1; d < SCAN_T; d <<= 1) {
        int add = (t >= d) ? sh[t - d] : 0;
        __syncthreads();
        sh[t] += add;
        __syncthreads();
    }
    int run = bbase[blockIdx.x] + sh[t] - tsum;
#pragma unroll
    for (int i = 0; i < SCAN_E; ++i) {
        int idx = lo + i;
        if (idx < M) C[idx] = run;
        run += vals[i];
    }
}

// k3: scatter edges into bucket-grouped ebuf. Cursors from transposed C.
__global__ void coarse_scatter(const int* __restrict__ row, const int* __restrict__ col,
                               const float* __restrict__ w, const int* __restrict__ O,
                               int2* __restrict__ ebuf, int n_edges, int ncb, int nblk) {
    __shared__ int cur[128];
    const int t = threadIdx.x;
    if (t < ncb) cur[t] = O[t * nblk + blockIdx.x];
    __syncthreads();
    const int base = blockIdx.x * EPB;
    const int end = min(base + EPB, n_edges);
    for (int i = base + t; i < end; i += P1_T) {
        int r = row[i];
        int pos = atomicAdd(&cur[r >> CB_SHIFT], 1);
        ebuf[pos] = make_int2(((r & (CB_ROWS - 1)) << COLBITS) | col[i], __float_as_int(w[i]));
    }
}

// k4: one block per coarse bucket. LDS 1024-row hist + scan -> off[r];
// permute the bucket's contiguous (L2-resident) segment into row order.
__global__ void fine_localize(const int2* __restrict__ ebuf, const int* __restrict__ O,
                              int ncb, int nblk, int n_edges,
                              int2* __restrict__ colw, int* __restrict__ off, int n_nodes) {
    const int b = blockIdx.x;
    const int base = O[b * nblk];
    const int endp = (b + 1 < ncb) ? O[(b + 1) * nblk] : n_edges;
    const int t = threadIdx.x;

    __shared__ int cnt[CB_ROWS];
    __shared__ int scn[CB_ROWS];
    __shared__ int cur[CB_ROWS];

    cnt[t] = 0;
    __syncthreads();
    for (int i = base + t; i < endp; i += CB_ROWS)
        atomicAdd(&cnt[ebuf[i].x >> COLBITS], 1);
    __syncthreads();

    scn[t] = cnt[t];
    __syncthreads();
    for (int d = 1; d < CB_ROWS; d <<= 1) {
        int add = (t >= d) ? scn[t - d] : 0;
        __syncthreads();
        scn[t] += add;
        __syncthreads();
    }
    const int e0 = scn[t] - cnt[t];
    const int r = b * CB_ROWS + t;
    if (r < n_nodes) off[r] = base + e0;
    cur[t] = e0;
    __syncthreads();

    for (int i = base + t; i < endp; i += CB_ROWS) {
        int2 ev = ebuf[i];
        int lr = ev.x >> COLBITS;
        int pos = base + atomicAdd(&cur[lr], 1);
        colw[pos] = make_int2(ev.x & ((1 << COLBITS) - 1), ev.y);
    }
}

// ---------------- atomic-free SpMV layer ----------------
__global__ void spmv_layer(const float* __restrict__ X, const int* __restrict__ off,
                           const int2* __restrict__ colw, float* __restrict__ out,
                           int n_nodes) {
    long tid = (long)blockIdx.x * blockDim.x + threadIdx.x;
    int r = (int)(tid >> 3);
    int q = (int)(tid & 7);
    if (r >= n_nodes) return;

    const int start = off[r];
    const int end   = off[r + 1];

    float4 acc = make_float4(0.f, 0.f, 0.f, 0.f);
    int k = start;
    for (; k + 4 <= end; k += 4) {
        int2 cw0 = colw[k + 0];
        int2 cw1 = colw[k + 1];
        int2 cw2 = colw[k + 2];
        int2 cw3 = colw[k + 3];
        const float4 v0 = *reinterpret_cast<const float4*>(X + (size_t)cw0.x * EMB_DIM + q * 4);
        const float4 v1 = *reinterpret_cast<const float4*>(X + (size_t)cw1.x * EMB_DIM + q * 4);
        const float4 v2 = *reinterpret_cast<const float4*>(X + (size_t)cw2.x * EMB_DIM + q * 4);
        const float4 v3 = *reinterpret_cast<const float4*>(X + (size_t)cw3.x * EMB_DIM + q * 4);
        const float w0 = __int_as_float(cw0.y), w1 = __int_as_float(cw1.y);
        const float w2 = __int_as_float(cw2.y), w3 = __int_as_float(cw3.y);
        acc.x += w0 * v0.x; acc.y += w0 * v0.y; acc.z += w0 * v0.z; acc.w += w0 * v0.w;
        acc.x += w1 * v1.x; acc.y += w1 * v1.y; acc.z += w1 * v1.z; acc.w += w1 * v1.w;
        acc.x += w2 * v2.x; acc.y += w2 * v2.y; acc.z += w2 * v2.z; acc.w += w2 * v2.w;
        acc.x += w3 * v3.x; acc.y += w3 * v3.y; acc.z += w3 * v3.z; acc.w += w3 * v3.w;
    }
    for (; k < end; ++k) {
        int2 cw = colw[k];
        const float wt = __int_as_float(cw.y);
        const float4 v = *reinterpret_cast<const float4*>(X + (size_t)cw.x * EMB_DIM + q * 4);
        acc.x += wt * v.x; acc.y += wt * v.y; acc.z += wt * v.z; acc.w += wt * v.w;
    }
    *reinterpret_cast<float4*>(out + (size_t)r * EMB_DIM + q * 4) = acc;
}

// ---------------- fallback (atomic scatter) ----------------
__global__ void lightgcn_scatter(const float* __restrict__ X, const float* __restrict__ w,
                                 const int* __restrict__ row, const int* __restrict__ col,
                                 float* __restrict__ out, int n_edges) {
    long tid = (long)blockIdx.x * blockDim.x + threadIdx.x;
    int e = (int)(tid >> 3);
    int q = (int)(tid & 7);
    if (e >= n_edges) return;
    const int r = row[e];
    const int c = col[e];
    const float wt = w[e];
    const float4 v = *reinterpret_cast<const float4*>(X + (size_t)c * EMB_DIM + q * 4);
    float* o = out + (size_t)r * EMB_DIM + q * 4;
    atomicAdd(o + 0, wt * v.x);
    atomicAdd(o + 1, wt * v.y);
    atomicAdd(o + 2, wt * v.z);
    atomicAdd(o + 3, wt * v.w);
}

extern "C" void kernel_launch(void* const* d_in, const int* in_sizes, int n_in,
                              void* d_out, int out_size, void* d_ws, size_t ws_size,
                              hipStream_t stream) {
    const float* emb = (const float*)d_in[0];
    const float* w   = (const float*)d_in[1];
    const int*   row = (const int*)d_in[2];
    const int*   col = (const int*)d_in[3];
    // d_in[4] = num_layers (device scalar); fixed at 3 for this problem.

    const int n_nodes = in_sizes[0] / EMB_DIM;
    const int n_edges = in_sizes[1];

    float* out = (float*)d_out;
    const size_t xbytes = (size_t)n_nodes * EMB_DIM * sizeof(float);

    const int ncb  = (n_nodes + CB_ROWS - 1) / CB_ROWS;   // coarse buckets (98)
    const int nblk = (n_edges + EPB - 1) / EPB;           // partition blocks (391)
    const int M    = ncb * nblk;                          // scan length (38318)
    const int nbs  = (M + SCAN_BLOCK - 1) / SCAN_BLOCK;   // scan blocks (19)

    // ---- workspace layout ----
    // ebuf (reused as tmpX after fine_localize) | colw | off | C | bsum
    const size_t ebuf_off = 0;
    const size_t ebuf_sz  = (((size_t)n_edges * 8 > xbytes ? (size_t)n_edges * 8 : xbytes) + 15) & ~(size_t)15;
    const size_t colw_off = ebuf_off + ebuf_sz;
    const size_t colw_sz  = ((size_t)n_edges * 8 + 15) & ~(size_t)15;
    const size_t off_off  = colw_off + colw_sz;
    const size_t off_sz   = ((size_t)(n_nodes + 2) * 4 + 15) & ~(size_t)15;
    const size_t C_off    = off_off + off_sz;
    const size_t C_sz     = ((size_t)M * 4 + 15) & ~(size_t)15;
    const size_t bsum_off = C_off + C_sz;
    const size_t bsum_sz  = ((size_t)(nbs + 1) * 4 + 15) & ~(size_t)15;
    const size_t need     = bsum_off + bsum_sz;

    if (ws_size < need || ncb > 128) {
        // Fallback: atomic path (needs only xbytes of ws)
        float* tmp = (float*)d_ws;
        const int threads = 256;
        const int blocks = (int)(((long)n_edges * 8 + threads - 1) / threads);
        hipMemsetAsync(d_out, 0, xbytes, stream);
        lightgcn_scatter<<<blocks, threads, 0, stream>>>(emb, w, row, col, out, n_edges);
        hipMemsetAsync(d_ws, 0, xbytes, stream);
        lightgcn_scatter<<<blocks, threads, 0, stream>>>(out, w, row, col, tmp, n_edges);
        hipMemsetAsync(d_out, 0, xbytes, stream);
        lightgcn_scatter<<<blocks, threads, 0, stream>>>(tmp, w, row, col, out, n_edges);
        return;
    }

    char* ws = (char*)d_ws;
    int2*  ebuf = (int2*)(ws + ebuf_off);
    float* tmpX = (float*)(ws + ebuf_off);   // alias: ebuf dead after fine_localize
    int2*  colw = (int2*)(ws + colw_off);
    int*   offs = (int*)(ws + off_off);
    int*   C    = (int*)(ws + C_off);
    int*   bsum = (int*)(ws + bsum_off);

    // ---- build CSR (once; reused for all 3 layers) ----
    coarse_count<<<nblk, P1_T, 0, stream>>>(row, C, n_edges, ncb, nblk);
    scan_block_sums<<<nbs, SCAN_T, 0, stream>>>(C, bsum, M);
    scan_bsum<<<1, SCAN_T, 0, stream>>>(bsum, nbs, offs, n_nodes);
    scan_block_write<<<nbs, SCAN_T, 0, stream>>>(C, bsum, M);
    coarse_scatter<<<nblk, P1_T, 0, stream>>>(row, col, w, C, ebuf, n_edges, ncb, nblk);
    fine_localize<<<ncb, CB_ROWS, 0, stream>>>(ebuf, C, ncb, nblk, n_edges, colw, offs, n_nodes);

    // ---- 3 atomic-free layers ----
    const int threads = 256;
    const int rblocks = (int)(((long)n_nodes * 8 + threads - 1) / threads);
    spmv_layer<<<rblocks, threads, 0, stream>>>(emb,  offs, colw, out,  n_nodes);
    spmv_layer<<<rblocks, threads, 0, stream>>>(out,  offs, colw, tmpX, n_nodes);
    spmv_layer<<<rblocks, threads, 0, stream>>>(tmpX, offs, colw, out,  n_nodes);
}